// Round 2
// baseline (505.684 us; speedup 1.0000x reference)
//
#include <hip/hip_runtime.h>

// Pipeline (R14 = R13 + k_mm software-pipelined W prefetch + fused wprep):
//   A  = relu([x|st]@W1+b1)                 [N,128] mm1  (fp32 VALU)
//   h0 = bf16(dis*relu(A@W2+b2))            [N,64]  mm2  (fp32 VALU, dis-scaled)
//   a0 = bf16(dis[d]*(sum h0[s] + h0[d]))   [N,64]  agg0 (unweighted gather)
//   h1 = bf16(relu(a0@Wg0 + bg0))           [N,128] mmx3 (MFMA, bias+relu)
//   P  = bf16(dis*(h1@Wg1))                 [N,128] mmx4 (MFMA, dis-scaled)
//   h2 = bf16(relu(dis[d]*(sum+self)+bg1))  [N,128] agg1
//   Q  = bf16(dis*(h2@Wg2))                 [N,64]  mmx5 (MFMA, dis-scaled)
//   out= dis[d]*(sum+self)+bg2              [N,64]  agg2 -> d_out (fp32)
//
// R13 post-mortem: mm1 at 68.7us, VALUBusy 25.6%, SGPR=112/VGPR=40 -> compiler
// s_loads W rows wave-uniformly but with zero prefetch distance; each FMA block
// stalls ~200cy on lgkmcnt. R14: explicit 2-buffer (wA/wB) row prefetch with
// static indices (runtime-indexed ext arrays would spill to scratch).
// Math: out[d] = dis[d]*(sum_s dis[s]*P[s] + dis[d]*P[d]); with P'[i]=dis[i]*P[i]
// this is dis[d]*(sum_s P'[s] + P'[d]) -- per-edge weights vanish.
// MFMA layouts (guide-verified): A[m=lane&15][k=(lane>>4)*8+j], B mirrored,
// C/D[row=(lane>>4)*4+reg][col=lane&15].

__device__ __forceinline__ unsigned short bf16rne(float f) {
    unsigned u = __float_as_uint(f);
    unsigned r = (u + 0x7fffu + ((u >> 16) & 1u)) >> 16;
    return (unsigned short)r;
}
__device__ __forceinline__ float bf16lo(unsigned v) { return __uint_as_float(v << 16); }
__device__ __forceinline__ float bf16hi(unsigned v) { return __uint_as_float(v & 0xffff0000u); }

using bf16x8 = __attribute__((ext_vector_type(8))) short;
using f32x4  = __attribute__((ext_vector_type(4))) float;

// ---------------- graph preprocessing: bucketed CSR (dst>>8 buckets) --------

__global__ __launch_bounds__(256) void k_hist(const int* __restrict__ dst, int e, int nb,
                                              int* __restrict__ gh) {
    __shared__ int h[512];
    const int t = threadIdx.x;
    h[t] = 0; h[t + 256] = 0;
    __syncthreads();
    const int base = blockIdx.x * 4096;
    const int end = min(base + 4096, e);
    for (int i = base + t; i < end; i += 256) atomicAdd(&h[dst[i] >> 8], 1);
    __syncthreads();
    for (int b = t; b < nb; b += 256)
        if (h[b]) atomicAdd(&gh[b], h[b]);
}

__global__ __launch_bounds__(512) void k_scan(const int* __restrict__ gh, int nb, int e, int n,
                                              int* __restrict__ bbase, int* __restrict__ gcur,
                                              int* __restrict__ offs) {
    __shared__ int sm[512];
    const int t = threadIdx.x;
    int v = (t < nb) ? gh[t] : 0;
    sm[t] = v;
    __syncthreads();
    for (int off = 1; off < 512; off <<= 1) {
        int add = (t >= off) ? sm[t - off] : 0;
        __syncthreads();
        sm[t] += add;
        __syncthreads();
    }
    if (t < nb) {
        int excl = sm[t] - v;
        bbase[t] = excl;
        gcur[t] = excl;
    }
    if (t == 0) { bbase[nb] = e; offs[n] = e; }
}

__global__ __launch_bounds__(256) void k_scatter1(const int* __restrict__ src,
                                                  const int* __restrict__ dst, int e, int nb,
                                                  int* __restrict__ gcur,
                                                  int2* __restrict__ ep) {
    __shared__ int h[512];
    __shared__ int cbase[512];
    const int t = threadIdx.x;
    h[t] = 0; h[t + 256] = 0;
    __syncthreads();
    const int base = blockIdx.x * 4096;
    const int end = min(base + 4096, e);
    for (int i = base + t; i < end; i += 256) atomicAdd(&h[dst[i] >> 8], 1);
    __syncthreads();
    for (int b = t; b < nb; b += 256) {
        int c = h[b];
        cbase[b] = c ? atomicAdd(&gcur[b], c) : 0;
        h[b] = 0;
    }
    __syncthreads();
    for (int i = base + t; i < end; i += 256) {
        int d = dst[i];
        int bn = d >> 8;
        int r = atomicAdd(&h[bn], 1);
        ep[cbase[bn] + r] = make_int2(src[i], d);
    }
}

__global__ __launch_bounds__(256) void k_build(const int2* __restrict__ ep,
                                               const int* __restrict__ bbase, int n,
                                               int* __restrict__ offs,
                                               int* __restrict__ ssrc,
                                               float* __restrict__ dis) {
    __shared__ int cnt[256];
    __shared__ int sm[256];
    __shared__ int cur[256];
    const int t = threadIdx.x;
    const int b = blockIdx.x;
    const int lo = bbase[b];
    const int hi = bbase[b + 1];
    cnt[t] = 0;
    __syncthreads();
    for (int i = lo + t; i < hi; i += 256) atomicAdd(&cnt[ep[i].y & 255], 1);
    __syncthreads();
    int v = cnt[t];
    sm[t] = v;
    __syncthreads();
    for (int off = 1; off < 256; off <<= 1) {
        int add = (t >= off) ? sm[t - off] : 0;
        __syncthreads();
        sm[t] += add;
        __syncthreads();
    }
    const int excl = sm[t] - v;
    const int node = (b << 8) + t;
    if (node < n) {
        offs[node] = lo + excl;
        dis[node] = rsqrtf(1.0f + (float)v);
    }
    cur[t] = lo + excl;
    __syncthreads();
    for (int i = lo + t; i < hi; i += 256) {
        int2 p = ep[i];
        int pos = atomicAdd(&cur[p.y & 255], 1);
        ssrc[pos] = p.x;
    }
}

__global__ __launch_bounds__(256) void k_sort(const int* __restrict__ offs,
                                              int* __restrict__ ssrc, int n) {
    const int wv = threadIdx.x >> 6;
    const int lane = threadIdx.x & 63;
    const int node = blockIdx.x * 4 + wv;
    if (node >= n) return;
    const int jb = offs[node];
    const int je = offs[node + 1];
    const int len = je - jb;
    if (len <= 1) return;
    if (len <= 64) {
        int v = (lane < len) ? ssrc[jb + lane] : 0x7fffffff;
#pragma unroll
        for (int k = 2; k <= 64; k <<= 1) {
            for (int j = k >> 1; j > 0; j >>= 1) {
                int p = __shfl_xor(v, j);
                bool lower = (lane & j) == 0;
                bool asc = (lane & k) == 0;
                v = (lower == asc) ? min(v, p) : max(v, p);
            }
        }
        if (lane < len) ssrc[jb + lane] = v;
    } else if (lane == 0) {
        for (int a = jb + 1; a < je; a++) {
            int key = ssrc[a];
            int b = a - 1;
            while (b >= jb && ssrc[b] > key) { ssrc[b + 1] = ssrc[b]; b--; }
            ssrc[b + 1] = key;
        }
    }
}

// ---------------- W -> MFMA fragment-ordered bf16 (fused x3) ----------------
// Wf[((kt*CT+ct)*64+lane)*8 + j] = bf16(W[kt*32+(lane>>4)*8+j][ct*16+(lane&15)])
// One thread per bf16 element. Segments: [0,8192)=Wg0 64x128,
// [8192,24576)=Wg1 128x128, [24576,32768)=Wg2 128x64.

__global__ void k_wprep3(const float* __restrict__ W0, const float* __restrict__ W1,
                         const float* __restrict__ W2,
                         unsigned short* __restrict__ F0, unsigned short* __restrict__ F1,
                         unsigned short* __restrict__ F2) {
    int tid = blockIdx.x * 256 + threadIdx.x;
    const float* W;
    unsigned short* Wf;
    int FOUT, t;
    if (tid < 8192) { W = W0; Wf = F0; FOUT = 128; t = tid; }
    else if (tid < 24576) { W = W1; Wf = F1; FOUT = 128; t = tid - 8192; }
    else { W = W2; Wf = F2; FOUT = 64; t = tid - 24576; }
    const int CT = FOUT / 16;
    int j = t & 7;
    int lane = (t >> 3) & 63;
    int ct = (t >> 9) % CT;
    int kt = t / (512 * CT);
    int k = kt * 32 + (lane >> 4) * 8 + j;
    int c = ct * 16 + (lane & 15);
    Wf[t] = bf16rne(W[(size_t)k * FOUT + c]);
}

// ---------------- MFMA matmul: out[n,FOUT](bf16) = in[n,K](bf16) @ Wf -------
// Block = 64 nodes (4 waves x 16 rows). Wave computes 16 x FOUT via CT
// col-tiles of mfma_f32_16x16x32_bf16, KT = K/32 k-steps.
// BR: fused +bias, relu (conv0 post-agg). SCALE: fused *dis[row] (pre-agg).

template <int K, int FOUT, bool BR, bool SCALE>
__global__ __launch_bounds__(256) void k_mmx(const unsigned short* __restrict__ in,
                                             const unsigned short* __restrict__ Wf,
                                             const float* __restrict__ bias,
                                             const float* __restrict__ dis,
                                             unsigned short* __restrict__ out, int n) {
    constexpr int KT = K / 32;
    constexpr int CT = FOUT / 16;
    const int t = threadIdx.x;
    const int wv = t >> 6;
    const int lane = t & 63;
    const int rowBase = blockIdx.x * 64 + wv * 16;
    const int m = lane & 15;
    const int q = lane >> 4;

    f32x4 acc[CT];
#pragma unroll
    for (int c = 0; c < CT; c++) acc[c] = (f32x4){0.f, 0.f, 0.f, 0.f};

    int arow = rowBase + m;
    if (arow >= n) arow = n - 1;
    const unsigned short* ap = in + (size_t)arow * K + q * 8;
    const bf16x8* wfp = (const bf16x8*)Wf;

#pragma unroll
    for (int kt = 0; kt < KT; kt++) {
        bf16x8 a = *(const bf16x8*)(ap + kt * 32);
#pragma unroll
        for (int c = 0; c < CT; c++) {
            bf16x8 b = wfp[(kt * CT + c) * 64 + lane];
            acc[c] = __builtin_amdgcn_mfma_f32_16x16x32_bf16(a, b, acc[c], 0, 0, 0);
        }
    }

    float bv[CT];
    if constexpr (BR) {
#pragma unroll
        for (int c = 0; c < CT; c++) bv[c] = bias[c * 16 + m];
    }

    // D[row=(lane>>4)*4+r][col=lane&15] per col-tile
    const int crow = rowBase + q * 4;
#pragma unroll
    for (int r = 0; r < 4; r++) {
        int rr = crow + r;
        if (rr >= n) continue;
        float sc = 1.f;
        if constexpr (SCALE) sc = dis[rr];
#pragma unroll
        for (int c = 0; c < CT; c++) {
            float v = acc[c][r];
            if constexpr (SCALE) v *= sc;
            if constexpr (BR) v = fmaxf(v + bv[c], 0.f);
            out[(size_t)rr * FOUT + c * 16 + m] = bf16rne(v);
        }
    }
}

// ---------------- dense matmul (fp32 VALU, MLP only) ------------------------
// x-tile in LDS (4x wave reuse); W rows are wave-uniform (f0 readfirstlane'd
// -> scalar-pipe loads). R14: explicit 2-row register double-buffer (wA/wB,
// static-indexed) so the W load for row k+1 issues before the FMAs of row k.

template <int FIN1, int FIN2, int FOUT, bool BIAS, bool RELU, bool OBF16, bool SCALE>
__global__ __launch_bounds__(256) void k_mm(const float* __restrict__ in1,
                                            const float* __restrict__ in2,
                                            const float* __restrict__ W,
                                            const float* __restrict__ bias,
                                            const float* __restrict__ dis,
                                            void* __restrict__ outv, int n) {
    constexpr int FINT = FIN1 + FIN2;
    constexpr int ROWF = FINT + 4;
    constexpr int JPT = FOUT / 4;
    constexpr int NC4 = JPT / 4;
    constexpr int RS4 = FOUT / 4;  // W row stride in float4

    __shared__ float lds[64 * ROWF];

    const int t = threadIdx.x;
    const int base = blockIdx.x * 64;

    {
        constexpr int R4 = FIN1 / 4;
        const float4* g = (const float4*)in1;
        for (int i = t; i < 64 * R4; i += 256) {
            int r = i / R4, c = i % R4;
            float4 v = (base + r < n) ? g[(size_t)(base + r) * R4 + c]
                                      : make_float4(0.f, 0.f, 0.f, 0.f);
            *(float4*)&lds[r * ROWF + c * 4] = v;
        }
    }
    if constexpr (FIN2 > 0) {
        constexpr int R4 = FIN2 / 4;
        const float4* g = (const float4*)in2;
        for (int i = t; i < 64 * R4; i += 256) {
            int r = i / R4, c = i % R4;
            float4 v = (base + r < n) ? g[(size_t)(base + r) * R4 + c]
                                      : make_float4(0.f, 0.f, 0.f, 0.f);
            *(float4*)&lds[r * ROWF + FIN1 + c * 4] = v;
        }
    }
    __syncthreads();

    const int lane = t & 63;
    const int f0 = __builtin_amdgcn_readfirstlane((t >> 6) * JPT);

    float4 acc[NC4];
    if constexpr (BIAS) {
        const float4* b4 = (const float4*)(bias + f0);
#pragma unroll
        for (int i = 0; i < NC4; i++) acc[i] = b4[i];
    } else {
#pragma unroll
        for (int i = 0; i < NC4; i++) acc[i] = make_float4(0.f, 0.f, 0.f, 0.f);
    }

    const float4* wbase = (const float4*)(W + f0);
    float4 wA[NC4], wB[NC4];
#pragma unroll
    for (int i = 0; i < NC4; i++) wA[i] = wbase[i];

#define FMA_ARR(av, wr)                                                       \
    do {                                                                      \
        _Pragma("unroll")                                                     \
        for (int i = 0; i < NC4; i++) {                                       \
            acc[i].x = fmaf((av), wr[i].x, acc[i].x);                         \
            acc[i].y = fmaf((av), wr[i].y, acc[i].y);                         \
            acc[i].z = fmaf((av), wr[i].z, acc[i].z);                         \
            acc[i].w = fmaf((av), wr[i].w, acc[i].w);                         \
        }                                                                     \
    } while (0)

    const float* arow = &lds[lane * ROWF];
    for (int k = 0; k < FINT; k += 2) {
        const float4* wn = wbase + (size_t)(k + 1) * RS4;
#pragma unroll
        for (int i = 0; i < NC4; i++) wB[i] = wn[i];
        float2 a2 = *(const float2*)(arow + k);
        FMA_ARR(a2.x, wA);
        const float4* wn2 = wbase + (size_t)((k + 2 < FINT) ? k + 2 : FINT - 1) * RS4;
#pragma unroll
        for (int i = 0; i < NC4; i++) wA[i] = wn2[i];
        FMA_ARR(a2.y, wB);
    }
#undef FMA_ARR

    const int node = base + lane;
    if (node < n) {
        if constexpr (RELU) {
#pragma unroll
            for (int i = 0; i < NC4; i++) {
                acc[i].x = fmaxf(acc[i].x, 0.f);
                acc[i].y = fmaxf(acc[i].y, 0.f);
                acc[i].z = fmaxf(acc[i].z, 0.f);
                acc[i].w = fmaxf(acc[i].w, 0.f);
            }
        }
        if constexpr (SCALE) {
            const float sc = dis[node];
#pragma unroll
            for (int i = 0; i < NC4; i++) {
                acc[i].x *= sc; acc[i].y *= sc;
                acc[i].z *= sc; acc[i].w *= sc;
            }
        }
        if constexpr (OBF16) {
            unsigned short* orow = (unsigned short*)outv + (size_t)node * FOUT + f0;
#pragma unroll
            for (int i = 0; i < NC4; i++) {
                ushort4 r;
                r.x = bf16rne(acc[i].x); r.y = bf16rne(acc[i].y);
                r.z = bf16rne(acc[i].z); r.w = bf16rne(acc[i].w);
                *(ushort4*)(orow + i * 4) = r;
            }
        } else {
            float4* orow = (float4*)((float*)outv + (size_t)node * FOUT + f0);
#pragma unroll
            for (int i = 0; i < NC4; i++) orow[i] = acc[i];
        }
    }
}

// ---------------- GCN aggregation (bf16 rows, half-wave pairing) ------------
// Inputs are dis-prescaled (P'[i] = dis[i]*P[i]) so the inner loop is a pure
// unweighted gather-add; dis[node] is applied once in the epilogue:
//   v = dis[node]*(sum_nb + self) [+ bias] [relu]
// OB: output bf16 (intermediates) else fp32 (final).

template <int F, bool RELU, bool OB, bool BIAS>
__global__ __launch_bounds__(256) void k_agg(const unsigned short* __restrict__ hW,
                                             const float* __restrict__ bias,
                                             const float* __restrict__ dis,
                                             const int* __restrict__ offs,
                                             const int* __restrict__ ssrc,
                                             void* __restrict__ outv, int n) {
    constexpr int FPL = F / 32;
    const int wv = threadIdx.x >> 6;
    const int lane = threadIdx.x & 63;
    const int node = blockIdx.x * 4 + wv;
    if (node >= n) return;
    const int g = lane >> 5;
    const int hl = lane & 31;
    const int jb = offs[node];
    const int je = offs[node + 1];

    float a0 = 0.f, a1 = 0.f, a2 = 0.f, a3 = 0.f;
    const unsigned short* lbase = hW + hl * FPL;

#define ROW_ADD(sidx)                                                               \
    do {                                                                            \
        if constexpr (FPL == 4) {                                                   \
            uint2 rv = *(const uint2*)(lbase + (size_t)(sidx) * F);                 \
            a0 += bf16lo(rv.x);                                                     \
            a1 += bf16hi(rv.x);                                                     \
            a2 += bf16lo(rv.y);                                                     \
            a3 += bf16hi(rv.y);                                                     \
        } else {                                                                    \
            unsigned rv = *(const unsigned*)(lbase + (size_t)(sidx) * F);           \
            a0 += bf16lo(rv);                                                       \
            a1 += bf16hi(rv);                                                       \
        }                                                                           \
    } while (0)

    int j = jb;
    for (; j + 8 <= je; j += 8) {
        int sv = ssrc[j + (lane & 7)];
        int s0 = __shfl(sv, 0 + g);
        int s1 = __shfl(sv, 2 + g);
        int s2 = __shfl(sv, 4 + g);
        int s3 = __shfl(sv, 6 + g);
        ROW_ADD(s0);
        ROW_ADD(s1);
        ROW_ADD(s2);
        ROW_ADD(s3);
    }
    for (; j + 2 <= je; j += 2) {
        int s = ssrc[j + g];
        ROW_ADD(s);
    }
    if (j < je) {
        int st = ssrc[j];
        if (g == 0) ROW_ADD(st);
    }
#undef ROW_ADD

    a0 += __shfl_xor(a0, 32);
    a1 += __shfl_xor(a1, 32);
    if constexpr (FPL == 4) {
        a2 += __shfl_xor(a2, 32);
        a3 += __shfl_xor(a3, 32);
    }

    if (g == 0) {
        const float di = dis[node];
        if constexpr (FPL == 4) {
            uint2 sv = *(const uint2*)(hW + (size_t)node * F + hl * 4);
            float v0 = (a0 + bf16lo(sv.x)) * di;
            float v1 = (a1 + bf16hi(sv.x)) * di;
            float v2 = (a2 + bf16lo(sv.y)) * di;
            float v3 = (a3 + bf16hi(sv.y)) * di;
            if constexpr (BIAS) {
                float4 bb = *(const float4*)(bias + hl * 4);
                v0 += bb.x; v1 += bb.y; v2 += bb.z; v3 += bb.w;
            }
            if (RELU) {
                v0 = fmaxf(v0, 0.f); v1 = fmaxf(v1, 0.f);
                v2 = fmaxf(v2, 0.f); v3 = fmaxf(v3, 0.f);
            }
            if constexpr (OB) {
                ushort4 o;
                o.x = bf16rne(v0); o.y = bf16rne(v1);
                o.z = bf16rne(v2); o.w = bf16rne(v3);
                *(ushort4*)((unsigned short*)outv + (size_t)node * F + hl * 4) = o;
            } else {
                *(float4*)((float*)outv + (size_t)node * F + hl * 4) =
                    make_float4(v0, v1, v2, v3);
            }
        } else {
            unsigned sv = *(const unsigned*)(hW + (size_t)node * F + hl * 2);
            float v0 = (a0 + bf16lo(sv)) * di;
            float v1 = (a1 + bf16hi(sv)) * di;
            if constexpr (BIAS) {
                float2 bb = *(const float2*)(bias + hl * 2);
                v0 += bb.x; v1 += bb.y;
            }
            if (RELU) { v0 = fmaxf(v0, 0.f); v1 = fmaxf(v1, 0.f); }
            if constexpr (OB) {
                ushort2 o;
                o.x = bf16rne(v0); o.y = bf16rne(v1);
                *(ushort2*)((unsigned short*)outv + (size_t)node * F + hl * 2) = o;
            } else {
                *(float2*)((float*)outv + (size_t)node * F + hl * 2) =
                    make_float2(v0, v1);
            }
        }
    }
}

// ---------------- launch -----------------------------------------------------

extern "C" void kernel_launch(void* const* d_in, const int* in_sizes, int n_in,
                              void* d_out, int out_size, void* d_ws, size_t ws_size,
                              hipStream_t stream) {
    const float* x   = (const float*)d_in[0];
    const float* st  = (const float*)d_in[1];
    const int*   src = (const int*)d_in[2];
    const int*   dst = (const int*)d_in[3];
    const float* W1  = (const float*)d_in[4];
    const float* b1  = (const float*)d_in[5];
    const float* W2  = (const float*)d_in[6];
    const float* b2  = (const float*)d_in[7];
    const float* Wg0 = (const float*)d_in[8];
    const float* bg0 = (const float*)d_in[9];
    const float* Wg1 = (const float*)d_in[10];
    const float* bg1 = (const float*)d_in[11];
    const float* Wg2 = (const float*)d_in[12];
    const float* bg2 = (const float*)d_in[13];

    const int n = in_sizes[0] / 64;  // IN_DIM = 64
    const int e = in_sizes[2];
    const int nb = (n + 255) >> 8;

    char* wp = (char*)d_ws;
    auto carve = [&](size_t bytes) {
        void* p = (void*)wp;
        wp += (bytes + 255) & ~(size_t)255;
        return p;
    };
    int*   ghist = (int*)carve(512 * 4);
    int*   gcur  = (int*)carve(512 * 4);
    int*   bbase = (int*)carve(513 * 4);
    int*   offs  = (int*)carve((size_t)(n + 1) * 4);
    float* dis   = (float*)carve((size_t)n * 4);
    int*   ssrc  = (int*)carve((size_t)e * 4);
    char*  R3    = (char*)carve((size_t)n * 128 * 4);  // ep -> M1 -> h1|h2
    char*  R2    = (char*)carve((size_t)n * 64 * 2);   // h0 -> Q
    unsigned short* W0f = (unsigned short*)carve((size_t)64 * 128 * 2);
    unsigned short* W1f = (unsigned short*)carve((size_t)128 * 128 * 2);
    unsigned short* W2f = (unsigned short*)carve((size_t)128 * 64 * 2);

    // aliases (stream-ordered lifetimes):
    int2* ep = (int2*)R3;                                 // dead after k_build
    float* M1 = (float*)R3;                               // mm1 out, dead after mm2
    unsigned short* h1 = (unsigned short*)R3;             // mmx3 out (n*128 bf16)
    unsigned short* h2 = (unsigned short*)(R3 + (size_t)n * 128 * 2);  // agg1 out
    unsigned short* h0 = (unsigned short*)R2;             // mm2 out (dis-scaled)
    unsigned short* Q  = (unsigned short*)R2;             // mmx5 out (dis-scaled)
    unsigned short* a0 = (unsigned short*)d_out;          // agg0 out (n*64 bf16)
    unsigned short* P  = (unsigned short*)d_out;          // mmx4 out (n*128 bf16)

    hipMemsetAsync(ghist, 0, 512 * 4, stream);

    const int gN64 = (n + 63) / 64;
    const int gAgg = (n + 3) / 4;
    const int gE4k = (e + 4095) / 4096;

    // graph prep
    k_hist<<<gE4k, 256, 0, stream>>>(dst, e, nb, ghist);
    k_scan<<<1, 512, 0, stream>>>(ghist, nb, e, n, bbase, gcur, offs);
    k_scatter1<<<gE4k, 256, 0, stream>>>(src, dst, e, nb, gcur, ep);
    k_build<<<nb, 256, 0, stream>>>(ep, bbase, n, offs, ssrc, dis);
    k_sort<<<gAgg, 256, 0, stream>>>(offs, ssrc, n);

    // W fragment prep (fused): 8192 + 16384 + 8192 elements = 128 blocks
    k_wprep3<<<128, 256, 0, stream>>>(Wg0, Wg1, Wg2, W0f, W1f, W2f);

    // MLP (fp32 VALU); mm2 output is dis-prescaled for agg0
    k_mm<64, 32, 128, true, true, false, false><<<gN64, 256, 0, stream>>>(
        x, st, W1, b1, nullptr, M1, n);
    k_mm<128, 0, 64, true, true, true, true><<<gN64, 256, 0, stream>>>(
        M1, nullptr, W2, b2, dis, h0, n);

    // conv0: agg FIRST at F=64 (agg(h)@W == agg(h@W)), then MFMA w/ bias+relu
    k_agg<64, false, true, false><<<gAgg, 256, 0, stream>>>(h0, nullptr, dis, offs, ssrc, a0, n);
    k_mmx<64, 128, true, false><<<gN64, 256, 0, stream>>>(a0, W0f, bg0, nullptr, h1, n);

    // conv1: MFMA mm (dis-prescaled) -> agg@128 (dis+bias+relu, bf16 out)
    k_mmx<128, 128, false, true><<<gN64, 256, 0, stream>>>(h1, W1f, nullptr, dis, P, n);
    k_agg<128, true, true, true><<<gAgg, 256, 0, stream>>>(P, bg1, dis, offs, ssrc, h2, n);

    // conv2: MFMA mm (dis-prescaled) -> agg@64 (dis+bias, fp32 out) -> d_out
    k_mmx<128, 64, false, true><<<gN64, 256, 0, stream>>>(h2, W2f, nullptr, dis, Q, n);
    k_agg<64, false, false, true><<<gAgg, 256, 0, stream>>>(Q, bg2, dis, offs, ssrc,
                                                            (float*)d_out, n);
}

// Round 3
// 440.274 us; speedup vs baseline: 1.1486x; 1.1486x over previous
//
#include <hip/hip_runtime.h>

// Pipeline (R15: entire dense chain on MFMA; fp32 VALU k_mm deleted):
//   A  = bf16(relu([x|st]@W1+b1))           [N,128] mmx1 (MFMA, fp32->bf16 in-reg)
//   h0 = bf16(dis*relu(A@W2+b2))            [N,64]  mmx2 (MFMA, bias+relu+scale)
//   a0 = bf16(dis[d]*(sum h0[s] + h0[d]))   [N,64]  agg0 (unweighted gather)
//   h1 = bf16(relu(a0@Wg0 + bg0))           [N,128] mmx3 (MFMA, bias+relu)
//   P  = bf16(dis*(h1@Wg1))                 [N,128] mmx4 (MFMA, scale)
//   h2 = bf16(relu(dis[d]*(sum+self)+bg1))  [N,128] agg1
//   Q  = bf16(dis*(h2@Wg2))                 [N,64]  mmx5 (MFMA, scale)
//   out= dis[d]*(sum+self)+bg2              [N,64]  agg2 -> d_out (fp32)
//
// R14 post-mortem: float2 LDS reads in k_mm caused 4-way bank conflicts
// (ROWF=100 stride = 4 dwords mod 32; b64 processes 32 lanes/phase vs b128's
// 16) -> 600K conflicts, VALUBusy 19.7%, 86us. Structural fix: fp32 VALU
// matmul floor is 15.6us and we never got under 68; the MFMA k_mmx shapes
// run <15us. So mm1/mm2 now MFMA with bf16 inputs (x,st,W1,W2,A rounded).
// Math: out[d] = dis[d]*(sum_s dis[s]*P[s] + dis[d]*P[d]); with P'[i]=dis[i]*P[i]
// this is dis[d]*(sum_s P'[s] + P'[d]) -- per-edge weights vanish.
// MFMA layouts (guide-verified): A[m=lane&15][k=(lane>>4)*8+j], B mirrored,
// C/D[row=(lane>>4)*4+reg][col=lane&15].

__device__ __forceinline__ unsigned short bf16rne(float f) {
    unsigned u = __float_as_uint(f);
    unsigned r = (u + 0x7fffu + ((u >> 16) & 1u)) >> 16;
    return (unsigned short)r;
}
__device__ __forceinline__ float bf16lo(unsigned v) { return __uint_as_float(v << 16); }
__device__ __forceinline__ float bf16hi(unsigned v) { return __uint_as_float(v & 0xffff0000u); }

using bf16x8 = __attribute__((ext_vector_type(8))) short;
using f32x4  = __attribute__((ext_vector_type(4))) float;

__device__ __forceinline__ bf16x8 pack8(float4 u, float4 v) {
    bf16x8 r;
    r[0] = (short)bf16rne(u.x); r[1] = (short)bf16rne(u.y);
    r[2] = (short)bf16rne(u.z); r[3] = (short)bf16rne(u.w);
    r[4] = (short)bf16rne(v.x); r[5] = (short)bf16rne(v.y);
    r[6] = (short)bf16rne(v.z); r[7] = (short)bf16rne(v.w);
    return r;
}

// ---------------- graph preprocessing: bucketed CSR (dst>>8 buckets) --------

__global__ __launch_bounds__(256) void k_hist(const int* __restrict__ dst, int e, int nb,
                                              int* __restrict__ gh) {
    __shared__ int h[512];
    const int t = threadIdx.x;
    h[t] = 0; h[t + 256] = 0;
    __syncthreads();
    const int base = blockIdx.x * 4096;
    const int end = min(base + 4096, e);
    for (int i = base + t; i < end; i += 256) atomicAdd(&h[dst[i] >> 8], 1);
    __syncthreads();
    for (int b = t; b < nb; b += 256)
        if (h[b]) atomicAdd(&gh[b], h[b]);
}

__global__ __launch_bounds__(512) void k_scan(const int* __restrict__ gh, int nb, int e, int n,
                                              int* __restrict__ bbase, int* __restrict__ gcur,
                                              int* __restrict__ offs) {
    __shared__ int sm[512];
    const int t = threadIdx.x;
    int v = (t < nb) ? gh[t] : 0;
    sm[t] = v;
    __syncthreads();
    for (int off = 1; off < 512; off <<= 1) {
        int add = (t >= off) ? sm[t - off] : 0;
        __syncthreads();
        sm[t] += add;
        __syncthreads();
    }
    if (t < nb) {
        int excl = sm[t] - v;
        bbase[t] = excl;
        gcur[t] = excl;
    }
    if (t == 0) { bbase[nb] = e; offs[n] = e; }
}

__global__ __launch_bounds__(256) void k_scatter1(const int* __restrict__ src,
                                                  const int* __restrict__ dst, int e, int nb,
                                                  int* __restrict__ gcur,
                                                  int2* __restrict__ ep) {
    __shared__ int h[512];
    __shared__ int cbase[512];
    const int t = threadIdx.x;
    h[t] = 0; h[t + 256] = 0;
    __syncthreads();
    const int base = blockIdx.x * 4096;
    const int end = min(base + 4096, e);
    for (int i = base + t; i < end; i += 256) atomicAdd(&h[dst[i] >> 8], 1);
    __syncthreads();
    for (int b = t; b < nb; b += 256) {
        int c = h[b];
        cbase[b] = c ? atomicAdd(&gcur[b], c) : 0;
        h[b] = 0;
    }
    __syncthreads();
    for (int i = base + t; i < end; i += 256) {
        int d = dst[i];
        int bn = d >> 8;
        int r = atomicAdd(&h[bn], 1);
        ep[cbase[bn] + r] = make_int2(src[i], d);
    }
}

__global__ __launch_bounds__(256) void k_build(const int2* __restrict__ ep,
                                               const int* __restrict__ bbase, int n,
                                               int* __restrict__ offs,
                                               int* __restrict__ ssrc,
                                               float* __restrict__ dis) {
    __shared__ int cnt[256];
    __shared__ int sm[256];
    __shared__ int cur[256];
    const int t = threadIdx.x;
    const int b = blockIdx.x;
    const int lo = bbase[b];
    const int hi = bbase[b + 1];
    cnt[t] = 0;
    __syncthreads();
    for (int i = lo + t; i < hi; i += 256) atomicAdd(&cnt[ep[i].y & 255], 1);
    __syncthreads();
    int v = cnt[t];
    sm[t] = v;
    __syncthreads();
    for (int off = 1; off < 256; off <<= 1) {
        int add = (t >= off) ? sm[t - off] : 0;
        __syncthreads();
        sm[t] += add;
        __syncthreads();
    }
    const int excl = sm[t] - v;
    const int node = (b << 8) + t;
    if (node < n) {
        offs[node] = lo + excl;
        dis[node] = rsqrtf(1.0f + (float)v);
    }
    cur[t] = lo + excl;
    __syncthreads();
    for (int i = lo + t; i < hi; i += 256) {
        int2 p = ep[i];
        int pos = atomicAdd(&cur[p.y & 255], 1);
        ssrc[pos] = p.x;
    }
}

__global__ __launch_bounds__(256) void k_sort(const int* __restrict__ offs,
                                              int* __restrict__ ssrc, int n) {
    const int wv = threadIdx.x >> 6;
    const int lane = threadIdx.x & 63;
    const int node = blockIdx.x * 4 + wv;
    if (node >= n) return;
    const int jb = offs[node];
    const int je = offs[node + 1];
    const int len = je - jb;
    if (len <= 1) return;
    if (len <= 64) {
        int v = (lane < len) ? ssrc[jb + lane] : 0x7fffffff;
#pragma unroll
        for (int k = 2; k <= 64; k <<= 1) {
            for (int j = k >> 1; j > 0; j >>= 1) {
                int p = __shfl_xor(v, j);
                bool lower = (lane & j) == 0;
                bool asc = (lane & k) == 0;
                v = (lower == asc) ? min(v, p) : max(v, p);
            }
        }
        if (lane < len) ssrc[jb + lane] = v;
    } else if (lane == 0) {
        for (int a = jb + 1; a < je; a++) {
            int key = ssrc[a];
            int b = a - 1;
            while (b >= jb && ssrc[b] > key) { ssrc[b + 1] = ssrc[b]; b--; }
            ssrc[b + 1] = key;
        }
    }
}

// ---------------- W -> MFMA fragment-ordered bf16 (fused x5) ----------------
// Wf[((kt*CT+ct)*64+lane)*8 + j] = bf16(W[kt*32+(lane>>4)*8+j][ct*16+(lane&15)])
// One thread per bf16 element. Segments:
//   [0,12288)       W1  96x128 -> Fa
//   [12288,20480)   W2 128x64  -> Fb
//   [20480,28672)   Wg0 64x128 -> F0
//   [28672,45056)   Wg1 128x128-> F1
//   [45056,53248)   Wg2 128x64 -> F2
// Grid must cover 53248 threads = 208 blocks.

__global__ void k_wprep5(const float* __restrict__ W1, const float* __restrict__ W2,
                         const float* __restrict__ G0, const float* __restrict__ G1,
                         const float* __restrict__ G2,
                         unsigned short* __restrict__ Fa, unsigned short* __restrict__ Fb,
                         unsigned short* __restrict__ F0, unsigned short* __restrict__ F1,
                         unsigned short* __restrict__ F2) {
    int t = blockIdx.x * 256 + threadIdx.x;
    const float* W;
    unsigned short* Wf;
    int FOUT;
    if (t < 12288) { W = W1; Wf = Fa; FOUT = 128; }
    else if (t < 20480) { t -= 12288; W = W2; Wf = Fb; FOUT = 64; }
    else if (t < 28672) { t -= 20480; W = G0; Wf = F0; FOUT = 128; }
    else if (t < 45056) { t -= 28672; W = G1; Wf = F1; FOUT = 128; }
    else { t -= 45056; W = G2; Wf = F2; FOUT = 64; }
    const int CT = FOUT / 16;
    int j = t & 7;
    int lane = (t >> 3) & 63;
    int ct = (t >> 9) % CT;
    int kt = t / (512 * CT);
    int k = kt * 32 + (lane >> 4) * 8 + j;
    int c = ct * 16 + (lane & 15);
    Wf[t] = bf16rne(W[(size_t)k * FOUT + c]);
}

// ---------------- MFMA matmul: out[n,FOUT](bf16) = in[n,K](bf16) @ Wf -------
// Block = 64 nodes (4 waves x 16 rows). Wave computes 16 x FOUT via CT
// col-tiles of mfma_f32_16x16x32_bf16, KT = K/32 k-steps.
// Epilogue order: (+bias) -> (relu) -> (*dis[row]).

template <int K, int FOUT, bool BIAS, bool RELU, bool SCALE>
__global__ __launch_bounds__(256) void k_mmx(const unsigned short* __restrict__ in,
                                             const unsigned short* __restrict__ Wf,
                                             const float* __restrict__ bias,
                                             const float* __restrict__ dis,
                                             unsigned short* __restrict__ out, int n) {
    constexpr int KT = K / 32;
    constexpr int CT = FOUT / 16;
    const int t = threadIdx.x;
    const int wv = t >> 6;
    const int lane = t & 63;
    const int rowBase = blockIdx.x * 64 + wv * 16;
    const int m = lane & 15;
    const int q = lane >> 4;

    f32x4 acc[CT];
#pragma unroll
    for (int c = 0; c < CT; c++) acc[c] = (f32x4){0.f, 0.f, 0.f, 0.f};

    int arow = rowBase + m;
    if (arow >= n) arow = n - 1;
    const unsigned short* ap = in + (size_t)arow * K + q * 8;
    const bf16x8* wfp = (const bf16x8*)Wf;

#pragma unroll
    for (int kt = 0; kt < KT; kt++) {
        bf16x8 a = *(const bf16x8*)(ap + kt * 32);
#pragma unroll
        for (int c = 0; c < CT; c++) {
            bf16x8 b = wfp[(kt * CT + c) * 64 + lane];
            acc[c] = __builtin_amdgcn_mfma_f32_16x16x32_bf16(a, b, acc[c], 0, 0, 0);
        }
    }

    float bv[CT];
    if constexpr (BIAS) {
#pragma unroll
        for (int c = 0; c < CT; c++) bv[c] = bias[c * 16 + m];
    }

    // D[row=(lane>>4)*4+r][col=lane&15] per col-tile
    const int crow = rowBase + q * 4;
#pragma unroll
    for (int r = 0; r < 4; r++) {
        int rr = crow + r;
        if (rr >= n) continue;
        float sc = 1.f;
        if constexpr (SCALE) sc = dis[rr];
#pragma unroll
        for (int c = 0; c < CT; c++) {
            float v = acc[c][r];
            if constexpr (BIAS) v += bv[c];
            if constexpr (RELU) v = fmaxf(v, 0.f);
            if constexpr (SCALE) v *= sc;
            out[(size_t)rr * FOUT + c * 16 + m] = bf16rne(v);
        }
    }
}

// ---------------- MFMA MLP layer 1: A = bf16(relu([x|st]@W1 + b1)) ----------
// K = 96 (64 from x, 32 from st), FOUT = 128. fp32 inputs converted to bf16
// fragments in registers (kt=0,1 from x; kt=2 from st).

__global__ __launch_bounds__(256) void k_mmx1(const float* __restrict__ x,
                                              const float* __restrict__ st,
                                              const unsigned short* __restrict__ Wf,
                                              const float* __restrict__ bias,
                                              unsigned short* __restrict__ out, int n) {
    constexpr int CT = 8;  // FOUT=128
    const int t = threadIdx.x;
    const int wv = t >> 6;
    const int lane = t & 63;
    const int rowBase = blockIdx.x * 64 + wv * 16;
    const int m = lane & 15;
    const int q = lane >> 4;

    f32x4 acc[CT];
#pragma unroll
    for (int c = 0; c < CT; c++) acc[c] = (f32x4){0.f, 0.f, 0.f, 0.f};

    int arow = rowBase + m;
    if (arow >= n) arow = n - 1;
    const float* xp = x + (size_t)arow * 64 + q * 8;
    const float* sp = st + (size_t)arow * 32 + q * 8;

    bf16x8 a0, a1, a2;
    {
        float4 u0 = *(const float4*)(xp);
        float4 v0 = *(const float4*)(xp + 4);
        a0 = pack8(u0, v0);
        float4 u1 = *(const float4*)(xp + 32);
        float4 v1 = *(const float4*)(xp + 36);
        a1 = pack8(u1, v1);
        float4 u2 = *(const float4*)(sp);
        float4 v2 = *(const float4*)(sp + 4);
        a2 = pack8(u2, v2);
    }

    const bf16x8* wfp = (const bf16x8*)Wf;
#pragma unroll
    for (int c = 0; c < CT; c++) {
        acc[c] = __builtin_amdgcn_mfma_f32_16x16x32_bf16(a0, wfp[c * 64 + lane], acc[c], 0, 0, 0);
        acc[c] = __builtin_amdgcn_mfma_f32_16x16x32_bf16(a1, wfp[(CT + c) * 64 + lane], acc[c], 0, 0, 0);
        acc[c] = __builtin_amdgcn_mfma_f32_16x16x32_bf16(a2, wfp[(2 * CT + c) * 64 + lane], acc[c], 0, 0, 0);
    }

    float bv[CT];
#pragma unroll
    for (int c = 0; c < CT; c++) bv[c] = bias[c * 16 + m];

    const int crow = rowBase + q * 4;
#pragma unroll
    for (int r = 0; r < 4; r++) {
        int rr = crow + r;
        if (rr >= n) continue;
#pragma unroll
        for (int c = 0; c < CT; c++) {
            float v = fmaxf(acc[c][r] + bv[c], 0.f);
            out[(size_t)rr * 128 + c * 16 + m] = bf16rne(v);
        }
    }
}

// ---------------- GCN aggregation (bf16 rows, half-wave pairing) ------------
// Inputs are dis-prescaled (P'[i] = dis[i]*P[i]) so the inner loop is a pure
// unweighted gather-add; dis[node] is applied once in the epilogue:
//   v = dis[node]*(sum_nb + self) [+ bias] [relu]
// OB: output bf16 (intermediates) else fp32 (final).

template <int F, bool RELU, bool OB, bool BIAS>
__global__ __launch_bounds__(256) void k_agg(const unsigned short* __restrict__ hW,
                                             const float* __restrict__ bias,
                                             const float* __restrict__ dis,
                                             const int* __restrict__ offs,
                                             const int* __restrict__ ssrc,
                                             void* __restrict__ outv, int n) {
    constexpr int FPL = F / 32;
    const int wv = threadIdx.x >> 6;
    const int lane = threadIdx.x & 63;
    const int node = blockIdx.x * 4 + wv;
    if (node >= n) return;
    const int g = lane >> 5;
    const int hl = lane & 31;
    const int jb = offs[node];
    const int je = offs[node + 1];

    float a0 = 0.f, a1 = 0.f, a2 = 0.f, a3 = 0.f;
    const unsigned short* lbase = hW + hl * FPL;

#define ROW_ADD(sidx)                                                               \
    do {                                                                            \
        if constexpr (FPL == 4) {                                                   \
            uint2 rv = *(const uint2*)(lbase + (size_t)(sidx) * F);                 \
            a0 += bf16lo(rv.x);                                                     \
            a1 += bf16hi(rv.x);                                                     \
            a2 += bf16lo(rv.y);                                                     \
            a3 += bf16hi(rv.y);                                                     \
        } else {                                                                    \
            unsigned rv = *(const unsigned*)(lbase + (size_t)(sidx) * F);           \
            a0 += bf16lo(rv);                                                       \
            a1 += bf16hi(rv);                                                       \
        }                                                                           \
    } while (0)

    int j = jb;
    for (; j + 8 <= je; j += 8) {
        int sv = ssrc[j + (lane & 7)];
        int s0 = __shfl(sv, 0 + g);
        int s1 = __shfl(sv, 2 + g);
        int s2 = __shfl(sv, 4 + g);
        int s3 = __shfl(sv, 6 + g);
        ROW_ADD(s0);
        ROW_ADD(s1);
        ROW_ADD(s2);
        ROW_ADD(s3);
    }
    for (; j + 2 <= je; j += 2) {
        int s = ssrc[j + g];
        ROW_ADD(s);
    }
    if (j < je) {
        int st = ssrc[j];
        if (g == 0) ROW_ADD(st);
    }
#undef ROW_ADD

    a0 += __shfl_xor(a0, 32);
    a1 += __shfl_xor(a1, 32);
    if constexpr (FPL == 4) {
        a2 += __shfl_xor(a2, 32);
        a3 += __shfl_xor(a3, 32);
    }

    if (g == 0) {
        const float di = dis[node];
        if constexpr (FPL == 4) {
            uint2 sv = *(const uint2*)(hW + (size_t)node * F + hl * 4);
            float v0 = (a0 + bf16lo(sv.x)) * di;
            float v1 = (a1 + bf16hi(sv.x)) * di;
            float v2 = (a2 + bf16lo(sv.y)) * di;
            float v3 = (a3 + bf16hi(sv.y)) * di;
            if constexpr (BIAS) {
                float4 bb = *(const float4*)(bias + hl * 4);
                v0 += bb.x; v1 += bb.y; v2 += bb.z; v3 += bb.w;
            }
            if (RELU) {
                v0 = fmaxf(v0, 0.f); v1 = fmaxf(v1, 0.f);
                v2 = fmaxf(v2, 0.f); v3 = fmaxf(v3, 0.f);
            }
            if constexpr (OB) {
                ushort4 o;
                o.x = bf16rne(v0); o.y = bf16rne(v1);
                o.z = bf16rne(v2); o.w = bf16rne(v3);
                *(ushort4*)((unsigned short*)outv + (size_t)node * F + hl * 4) = o;
            } else {
                *(float4*)((float*)outv + (size_t)node * F + hl * 4) =
                    make_float4(v0, v1, v2, v3);
            }
        } else {
            unsigned sv = *(const unsigned*)(hW + (size_t)node * F + hl * 2);
            float v0 = (a0 + bf16lo(sv)) * di;
            float v1 = (a1 + bf16hi(sv)) * di;
            if constexpr (BIAS) {
                float2 bb = *(const float2*)(bias + hl * 2);
                v0 += bb.x; v1 += bb.y;
            }
            if (RELU) { v0 = fmaxf(v0, 0.f); v1 = fmaxf(v1, 0.f); }
            if constexpr (OB) {
                ushort2 o;
                o.x = bf16rne(v0); o.y = bf16rne(v1);
                *(ushort2*)((unsigned short*)outv + (size_t)node * F + hl * 2) = o;
            } else {
                *(float2*)((float*)outv + (size_t)node * F + hl * 2) =
                    make_float2(v0, v1);
            }
        }
    }
}

// ---------------- launch -----------------------------------------------------

extern "C" void kernel_launch(void* const* d_in, const int* in_sizes, int n_in,
                              void* d_out, int out_size, void* d_ws, size_t ws_size,
                              hipStream_t stream) {
    const float* x   = (const float*)d_in[0];
    const float* st  = (const float*)d_in[1];
    const int*   src = (const int*)d_in[2];
    const int*   dst = (const int*)d_in[3];
    const float* W1  = (const float*)d_in[4];
    const float* b1  = (const float*)d_in[5];
    const float* W2  = (const float*)d_in[6];
    const float* b2  = (const float*)d_in[7];
    const float* Wg0 = (const float*)d_in[8];
    const float* bg0 = (const float*)d_in[9];
    const float* Wg1 = (const float*)d_in[10];
    const float* bg1 = (const float*)d_in[11];
    const float* Wg2 = (const float*)d_in[12];
    const float* bg2 = (const float*)d_in[13];

    const int n = in_sizes[0] / 64;  // IN_DIM = 64
    const int e = in_sizes[2];
    const int nb = (n + 255) >> 8;

    char* wp = (char*)d_ws;
    auto carve = [&](size_t bytes) {
        void* p = (void*)wp;
        wp += (bytes + 255) & ~(size_t)255;
        return p;
    };
    int*   ghist = (int*)carve(512 * 4);
    int*   gcur  = (int*)carve(512 * 4);
    int*   bbase = (int*)carve(513 * 4);
    int*   offs  = (int*)carve((size_t)(n + 1) * 4);
    float* dis   = (float*)carve((size_t)n * 4);
    int*   ssrc  = (int*)carve((size_t)e * 4);
    char*  R3    = (char*)carve((size_t)n * 128 * 4);  // ep -> A -> h1|h2
    char*  R2    = (char*)carve((size_t)n * 64 * 2);   // h0 -> Q
    unsigned short* Waf = (unsigned short*)carve((size_t)96 * 128 * 2);
    unsigned short* Wbf = (unsigned short*)carve((size_t)128 * 64 * 2);
    unsigned short* W0f = (unsigned short*)carve((size_t)64 * 128 * 2);
    unsigned short* W1f = (unsigned short*)carve((size_t)128 * 128 * 2);
    unsigned short* W2f = (unsigned short*)carve((size_t)128 * 64 * 2);

    // aliases (stream-ordered lifetimes):
    int2* ep = (int2*)R3;                                 // dead after k_build
    unsigned short* A  = (unsigned short*)R3;             // mmx1 out (n*128 bf16)
    unsigned short* h1 = (unsigned short*)R3;             // mmx3 out (A dead by then)
    unsigned short* h2 = (unsigned short*)(R3 + (size_t)n * 128 * 2);  // agg1 out
    unsigned short* h0 = (unsigned short*)R2;             // mmx2 out (dis-scaled)
    unsigned short* Q  = (unsigned short*)R2;             // mmx5 out (dis-scaled)
    unsigned short* a0 = (unsigned short*)d_out;          // agg0 out (n*64 bf16)
    unsigned short* P  = (unsigned short*)d_out;          // mmx4 out (n*128 bf16)

    hipMemsetAsync(ghist, 0, 512 * 4, stream);

    const int gN64 = (n + 63) / 64;
    const int gAgg = (n + 3) / 4;
    const int gE4k = (e + 4095) / 4096;

    // graph prep
    k_hist<<<gE4k, 256, 0, stream>>>(dst, e, nb, ghist);
    k_scan<<<1, 512, 0, stream>>>(ghist, nb, e, n, bbase, gcur, offs);
    k_scatter1<<<gE4k, 256, 0, stream>>>(src, dst, e, nb, gcur, ep);
    k_build<<<nb, 256, 0, stream>>>(ep, bbase, n, offs, ssrc, dis);
    k_sort<<<gAgg, 256, 0, stream>>>(offs, ssrc, n);

    // W fragment prep (fused x5): 53248 elements = 208 blocks
    k_wprep5<<<208, 256, 0, stream>>>(W1, W2, Wg0, Wg1, Wg2, Waf, Wbf, W0f, W1f, W2f);

    // MLP on MFMA: A = relu([x|st]@W1+b1); h0 = dis*relu(A@W2+b2)
    k_mmx1<<<gN64, 256, 0, stream>>>(x, st, Waf, b1, A, n);
    k_mmx<128, 64, true, true, true><<<gN64, 256, 0, stream>>>(A, Wbf, b2, dis, h0, n);

    // conv0: agg FIRST at F=64 (agg(h)@W == agg(h@W)), then MFMA w/ bias+relu
    k_agg<64, false, true, false><<<gAgg, 256, 0, stream>>>(h0, nullptr, dis, offs, ssrc, a0, n);
    k_mmx<64, 128, true, true, false><<<gN64, 256, 0, stream>>>(a0, W0f, bg0, nullptr, h1, n);

    // conv1: MFMA mm (dis-prescaled) -> agg@128 (dis+bias+relu, bf16 out)
    k_mmx<128, 128, false, false, true><<<gN64, 256, 0, stream>>>(h1, W1f, nullptr, dis, P, n);
    k_agg<128, true, true, true><<<gAgg, 256, 0, stream>>>(P, bg1, dis, offs, ssrc, h2, n);

    // conv2: MFMA mm (dis-prescaled) -> agg@64 (dis+bias, fp32 out) -> d_out
    k_mmx<128, 64, false, false, true><<<gN64, 256, 0, stream>>>(h2, W2f, nullptr, dis, Q, n);
    k_agg<64, false, false, true><<<gAgg, 256, 0, stream>>>(Q, bg2, dis, offs, ssrc,
                                                            (float*)d_out, n);
}

// Round 4
// 405.807 us; speedup vs baseline: 1.2461x; 1.0849x over previous
//
#include <hip/hip_runtime.h>

// Pipeline (R16 = R15 + wide-gather agg: uint4/lane row gathers, NG rows per
// load instruction (1 KiB/wave-instr), ssrc prefetch pipeline, shfl-tree reduce):
//   A  = bf16(relu([x|st]@W1+b1))           [N,128] mmx1 (MFMA, fp32->bf16 in-reg)
//   h0 = bf16(dis*relu(A@W2+b2))            [N,64]  mmx2 (MFMA, bias+relu+scale)
//   a0 = bf16(dis[d]*(sum h0[s] + h0[d]))   [N,64]  agg0 (unweighted gather)
//   h1 = bf16(relu(a0@Wg0 + bg0))           [N,128] mmx3 (MFMA, bias+relu)
//   P  = bf16(dis*(h1@Wg1))                 [N,128] mmx4 (MFMA, scale)
//   h2 = bf16(relu(dis[d]*(sum+self)+bg1))  [N,128] agg1
//   Q  = bf16(dis*(h2@Wg2))                 [N,64]  mmx5 (MFMA, scale)
//   out= dis[d]*(sum+self)+bg2              [N,64]  agg2 -> d_out (fp32)
//
// R15 post-mortem: aggs dominate (67us @ F=128), HBM 41%/VALU 40% -- latency
// bound: old scheme = 8B/lane uint2 gathers (2 rows per instr) + ssrc load in
// the serial chain (2 mem latencies per 8-edge chunk). R16 agg: group of F/8
// lanes gathers one row at 16B/lane; 64/(F/8) rows per instruction; ssrc for
// chunk j+8 prefetched during chunk j; epilogue shfl_xor tree (16,32 for
// F=128; 8,16,32 for F=64).
// Math: out[d] = dis[d]*(sum_s dis[s]*P[s] + dis[d]*P[d]); with P'[i]=dis[i]*P[i]
// this is dis[d]*(sum_s P'[s] + P'[d]) -- per-edge weights vanish.
// MFMA layouts (guide-verified): A[m=lane&15][k=(lane>>4)*8+j], B mirrored,
// C/D[row=(lane>>4)*4+reg][col=lane&15].

__device__ __forceinline__ unsigned short bf16rne(float f) {
    unsigned u = __float_as_uint(f);
    unsigned r = (u + 0x7fffu + ((u >> 16) & 1u)) >> 16;
    return (unsigned short)r;
}
__device__ __forceinline__ float bf16lo(unsigned v) { return __uint_as_float(v << 16); }
__device__ __forceinline__ float bf16hi(unsigned v) { return __uint_as_float(v & 0xffff0000u); }

using bf16x8 = __attribute__((ext_vector_type(8))) short;
using f32x4  = __attribute__((ext_vector_type(4))) float;

__device__ __forceinline__ bf16x8 pack8(float4 u, float4 v) {
    bf16x8 r;
    r[0] = (short)bf16rne(u.x); r[1] = (short)bf16rne(u.y);
    r[2] = (short)bf16rne(u.z); r[3] = (short)bf16rne(u.w);
    r[4] = (short)bf16rne(v.x); r[5] = (short)bf16rne(v.y);
    r[6] = (short)bf16rne(v.z); r[7] = (short)bf16rne(v.w);
    return r;
}

// ---------------- graph preprocessing: bucketed CSR (dst>>8 buckets) --------

__global__ __launch_bounds__(256) void k_hist(const int* __restrict__ dst, int e, int nb,
                                              int* __restrict__ gh) {
    __shared__ int h[512];
    const int t = threadIdx.x;
    h[t] = 0; h[t + 256] = 0;
    __syncthreads();
    const int base = blockIdx.x * 4096;
    const int end = min(base + 4096, e);
    for (int i = base + t; i < end; i += 256) atomicAdd(&h[dst[i] >> 8], 1);
    __syncthreads();
    for (int b = t; b < nb; b += 256)
        if (h[b]) atomicAdd(&gh[b], h[b]);
}

__global__ __launch_bounds__(512) void k_scan(const int* __restrict__ gh, int nb, int e, int n,
                                              int* __restrict__ bbase, int* __restrict__ gcur,
                                              int* __restrict__ offs) {
    __shared__ int sm[512];
    const int t = threadIdx.x;
    int v = (t < nb) ? gh[t] : 0;
    sm[t] = v;
    __syncthreads();
    for (int off = 1; off < 512; off <<= 1) {
        int add = (t >= off) ? sm[t - off] : 0;
        __syncthreads();
        sm[t] += add;
        __syncthreads();
    }
    if (t < nb) {
        int excl = sm[t] - v;
        bbase[t] = excl;
        gcur[t] = excl;
    }
    if (t == 0) { bbase[nb] = e; offs[n] = e; }
}

__global__ __launch_bounds__(256) void k_scatter1(const int* __restrict__ src,
                                                  const int* __restrict__ dst, int e, int nb,
                                                  int* __restrict__ gcur,
                                                  int2* __restrict__ ep) {
    __shared__ int h[512];
    __shared__ int cbase[512];
    const int t = threadIdx.x;
    h[t] = 0; h[t + 256] = 0;
    __syncthreads();
    const int base = blockIdx.x * 4096;
    const int end = min(base + 4096, e);
    for (int i = base + t; i < end; i += 256) atomicAdd(&h[dst[i] >> 8], 1);
    __syncthreads();
    for (int b = t; b < nb; b += 256) {
        int c = h[b];
        cbase[b] = c ? atomicAdd(&gcur[b], c) : 0;
        h[b] = 0;
    }
    __syncthreads();
    for (int i = base + t; i < end; i += 256) {
        int d = dst[i];
        int bn = d >> 8;
        int r = atomicAdd(&h[bn], 1);
        ep[cbase[bn] + r] = make_int2(src[i], d);
    }
}

__global__ __launch_bounds__(256) void k_build(const int2* __restrict__ ep,
                                               const int* __restrict__ bbase, int n,
                                               int* __restrict__ offs,
                                               int* __restrict__ ssrc,
                                               float* __restrict__ dis) {
    __shared__ int cnt[256];
    __shared__ int sm[256];
    __shared__ int cur[256];
    const int t = threadIdx.x;
    const int b = blockIdx.x;
    const int lo = bbase[b];
    const int hi = bbase[b + 1];
    cnt[t] = 0;
    __syncthreads();
    for (int i = lo + t; i < hi; i += 256) atomicAdd(&cnt[ep[i].y & 255], 1);
    __syncthreads();
    int v = cnt[t];
    sm[t] = v;
    __syncthreads();
    for (int off = 1; off < 256; off <<= 1) {
        int add = (t >= off) ? sm[t - off] : 0;
        __syncthreads();
        sm[t] += add;
        __syncthreads();
    }
    const int excl = sm[t] - v;
    const int node = (b << 8) + t;
    if (node < n) {
        offs[node] = lo + excl;
        dis[node] = rsqrtf(1.0f + (float)v);
    }
    cur[t] = lo + excl;
    __syncthreads();
    for (int i = lo + t; i < hi; i += 256) {
        int2 p = ep[i];
        int pos = atomicAdd(&cur[p.y & 255], 1);
        ssrc[pos] = p.x;
    }
}

__global__ __launch_bounds__(256) void k_sort(const int* __restrict__ offs,
                                              int* __restrict__ ssrc, int n) {
    const int wv = threadIdx.x >> 6;
    const int lane = threadIdx.x & 63;
    const int node = blockIdx.x * 4 + wv;
    if (node >= n) return;
    const int jb = offs[node];
    const int je = offs[node + 1];
    const int len = je - jb;
    if (len <= 1) return;
    if (len <= 64) {
        int v = (lane < len) ? ssrc[jb + lane] : 0x7fffffff;
#pragma unroll
        for (int k = 2; k <= 64; k <<= 1) {
            for (int j = k >> 1; j > 0; j >>= 1) {
                int p = __shfl_xor(v, j);
                bool lower = (lane & j) == 0;
                bool asc = (lane & k) == 0;
                v = (lower == asc) ? min(v, p) : max(v, p);
            }
        }
        if (lane < len) ssrc[jb + lane] = v;
    } else if (lane == 0) {
        for (int a = jb + 1; a < je; a++) {
            int key = ssrc[a];
            int b = a - 1;
            while (b >= jb && ssrc[b] > key) { ssrc[b + 1] = ssrc[b]; b--; }
            ssrc[b + 1] = key;
        }
    }
}

// ---------------- W -> MFMA fragment-ordered bf16 (fused x5) ----------------
// Wf[((kt*CT+ct)*64+lane)*8 + j] = bf16(W[kt*32+(lane>>4)*8+j][ct*16+(lane&15)])
// One thread per bf16 element. Segments:
//   [0,12288)       W1  96x128 -> Fa
//   [12288,20480)   W2 128x64  -> Fb
//   [20480,28672)   Wg0 64x128 -> F0
//   [28672,45056)   Wg1 128x128-> F1
//   [45056,53248)   Wg2 128x64 -> F2
// Grid must cover 53248 threads = 208 blocks.

__global__ void k_wprep5(const float* __restrict__ W1, const float* __restrict__ W2,
                         const float* __restrict__ G0, const float* __restrict__ G1,
                         const float* __restrict__ G2,
                         unsigned short* __restrict__ Fa, unsigned short* __restrict__ Fb,
                         unsigned short* __restrict__ F0, unsigned short* __restrict__ F1,
                         unsigned short* __restrict__ F2) {
    int t = blockIdx.x * 256 + threadIdx.x;
    const float* W;
    unsigned short* Wf;
    int FOUT;
    if (t < 12288) { W = W1; Wf = Fa; FOUT = 128; }
    else if (t < 20480) { t -= 12288; W = W2; Wf = Fb; FOUT = 64; }
    else if (t < 28672) { t -= 20480; W = G0; Wf = F0; FOUT = 128; }
    else if (t < 45056) { t -= 28672; W = G1; Wf = F1; FOUT = 128; }
    else { t -= 45056; W = G2; Wf = F2; FOUT = 64; }
    const int CT = FOUT / 16;
    int j = t & 7;
    int lane = (t >> 3) & 63;
    int ct = (t >> 9) % CT;
    int kt = t / (512 * CT);
    int k = kt * 32 + (lane >> 4) * 8 + j;
    int c = ct * 16 + (lane & 15);
    Wf[t] = bf16rne(W[(size_t)k * FOUT + c]);
}

// ---------------- MFMA matmul: out[n,FOUT](bf16) = in[n,K](bf16) @ Wf -------
// Block = 64 nodes (4 waves x 16 rows). Wave computes 16 x FOUT via CT
// col-tiles of mfma_f32_16x16x32_bf16, KT = K/32 k-steps.
// Epilogue order: (+bias) -> (relu) -> (*dis[row]).

template <int K, int FOUT, bool BIAS, bool RELU, bool SCALE>
__global__ __launch_bounds__(256) void k_mmx(const unsigned short* __restrict__ in,
                                             const unsigned short* __restrict__ Wf,
                                             const float* __restrict__ bias,
                                             const float* __restrict__ dis,
                                             unsigned short* __restrict__ out, int n) {
    constexpr int KT = K / 32;
    constexpr int CT = FOUT / 16;
    const int t = threadIdx.x;
    const int wv = t >> 6;
    const int lane = t & 63;
    const int rowBase = blockIdx.x * 64 + wv * 16;
    const int m = lane & 15;
    const int q = lane >> 4;

    f32x4 acc[CT];
#pragma unroll
    for (int c = 0; c < CT; c++) acc[c] = (f32x4){0.f, 0.f, 0.f, 0.f};

    int arow = rowBase + m;
    if (arow >= n) arow = n - 1;
    const unsigned short* ap = in + (size_t)arow * K + q * 8;
    const bf16x8* wfp = (const bf16x8*)Wf;

#pragma unroll
    for (int kt = 0; kt < KT; kt++) {
        bf16x8 a = *(const bf16x8*)(ap + kt * 32);
#pragma unroll
        for (int c = 0; c < CT; c++) {
            bf16x8 b = wfp[(kt * CT + c) * 64 + lane];
            acc[c] = __builtin_amdgcn_mfma_f32_16x16x32_bf16(a, b, acc[c], 0, 0, 0);
        }
    }

    float bv[CT];
    if constexpr (BIAS) {
#pragma unroll
        for (int c = 0; c < CT; c++) bv[c] = bias[c * 16 + m];
    }

    // D[row=(lane>>4)*4+r][col=lane&15] per col-tile
    const int crow = rowBase + q * 4;
#pragma unroll
    for (int r = 0; r < 4; r++) {
        int rr = crow + r;
        if (rr >= n) continue;
        float sc = 1.f;
        if constexpr (SCALE) sc = dis[rr];
#pragma unroll
        for (int c = 0; c < CT; c++) {
            float v = acc[c][r];
            if constexpr (BIAS) v += bv[c];
            if constexpr (RELU) v = fmaxf(v, 0.f);
            if constexpr (SCALE) v *= sc;
            out[(size_t)rr * FOUT + c * 16 + m] = bf16rne(v);
        }
    }
}

// ---------------- MFMA MLP layer 1: A = bf16(relu([x|st]@W1 + b1)) ----------
// K = 96 (64 from x, 32 from st), FOUT = 128. fp32 inputs converted to bf16
// fragments in registers (kt=0,1 from x; kt=2 from st).

__global__ __launch_bounds__(256) void k_mmx1(const float* __restrict__ x,
                                              const float* __restrict__ st,
                                              const unsigned short* __restrict__ Wf,
                                              const float* __restrict__ bias,
                                              unsigned short* __restrict__ out, int n) {
    constexpr int CT = 8;  // FOUT=128
    const int t = threadIdx.x;
    const int wv = t >> 6;
    const int lane = t & 63;
    const int rowBase = blockIdx.x * 64 + wv * 16;
    const int m = lane & 15;
    const int q = lane >> 4;

    f32x4 acc[CT];
#pragma unroll
    for (int c = 0; c < CT; c++) acc[c] = (f32x4){0.f, 0.f, 0.f, 0.f};

    int arow = rowBase + m;
    if (arow >= n) arow = n - 1;
    const float* xp = x + (size_t)arow * 64 + q * 8;
    const float* sp = st + (size_t)arow * 32 + q * 8;

    bf16x8 a0, a1, a2;
    {
        float4 u0 = *(const float4*)(xp);
        float4 v0 = *(const float4*)(xp + 4);
        a0 = pack8(u0, v0);
        float4 u1 = *(const float4*)(xp + 32);
        float4 v1 = *(const float4*)(xp + 36);
        a1 = pack8(u1, v1);
        float4 u2 = *(const float4*)(sp);
        float4 v2 = *(const float4*)(sp + 4);
        a2 = pack8(u2, v2);
    }

    const bf16x8* wfp = (const bf16x8*)Wf;
#pragma unroll
    for (int c = 0; c < CT; c++) {
        acc[c] = __builtin_amdgcn_mfma_f32_16x16x32_bf16(a0, wfp[c * 64 + lane], acc[c], 0, 0, 0);
        acc[c] = __builtin_amdgcn_mfma_f32_16x16x32_bf16(a1, wfp[(CT + c) * 64 + lane], acc[c], 0, 0, 0);
        acc[c] = __builtin_amdgcn_mfma_f32_16x16x32_bf16(a2, wfp[(2 * CT + c) * 64 + lane], acc[c], 0, 0, 0);
    }

    float bv[CT];
#pragma unroll
    for (int c = 0; c < CT; c++) bv[c] = bias[c * 16 + m];

    const int crow = rowBase + q * 4;
#pragma unroll
    for (int r = 0; r < 4; r++) {
        int rr = crow + r;
        if (rr >= n) continue;
#pragma unroll
        for (int c = 0; c < CT; c++) {
            float v = fmaxf(acc[c][r] + bv[c], 0.f);
            out[(size_t)rr * 128 + c * 16 + m] = bf16rne(v);
        }
    }
}

// ---------------- GCN aggregation (wide-gather, group-per-row) --------------
// Inputs are dis-prescaled (P'[i] = dis[i]*P[i]); inner loop = pure gather-add.
// Wave split into NG = 64/(F/8) groups of G = F/8 lanes; each group gathers
// one full row per load instruction at 16B/lane (uint4 = 8 bf16). 8-edge
// chunks; ssrc for chunk j+8 prefetched during chunk j. Epilogue: shfl_xor
// tree across groups, then v = (sum + self)*dis[node] [+bias] [relu].
// OB: output bf16 (intermediates) else fp32 (final).

template <int F, bool RELU, bool OB, bool BIAS>
__global__ __launch_bounds__(256) void k_agg(const unsigned short* __restrict__ hW,
                                             const float* __restrict__ bias,
                                             const float* __restrict__ dis,
                                             const int* __restrict__ offs,
                                             const int* __restrict__ ssrc,
                                             void* __restrict__ outv, int n) {
    constexpr int G = F / 8;    // lanes per row (16B each): 16 @F=128, 8 @F=64
    constexpr int NG = 64 / G;  // rows per load instr: 4 @F=128, 8 @F=64
    const int wv = threadIdx.x >> 6;
    const int lane = threadIdx.x & 63;
    const int node = blockIdx.x * 4 + wv;
    if (node >= n) return;
    const int grp = lane / G;
    const int gl = lane % G;
    const int jb = offs[node];
    const int je = offs[node + 1];

    float a0 = 0.f, a1 = 0.f, a2 = 0.f, a3 = 0.f;
    float a4 = 0.f, a5 = 0.f, a6 = 0.f, a7 = 0.f;
    const unsigned short* gbase = hW + gl * 8;

#define ROW_ADD(sidx)                                                           \
    do {                                                                        \
        uint4 rv = *(const uint4*)(gbase + (size_t)(sidx) * F);                 \
        a0 += bf16lo(rv.x); a1 += bf16hi(rv.x);                                 \
        a2 += bf16lo(rv.y); a3 += bf16hi(rv.y);                                 \
        a4 += bf16lo(rv.z); a5 += bf16hi(rv.z);                                 \
        a6 += bf16lo(rv.w); a7 += bf16hi(rv.w);                                 \
    } while (0)

    int j = jb;
    int svn = 0;
    if (j < je) svn = ssrc[min(j + (lane & 7), je - 1)];
    for (; j + 8 <= je; j += 8) {
        int sv = svn;
        int jn = j + 8;
        if (jn < je) svn = ssrc[min(jn + (lane & 7), je - 1)];
        if constexpr (NG == 4) {
            int s0 = __shfl(sv, grp);
            int s1 = __shfl(sv, grp + 4);
            ROW_ADD(s0);
            ROW_ADD(s1);
        } else {
            int s0 = __shfl(sv, grp);
            ROW_ADD(s0);
        }
    }
    {
        int rem = je - j;
        if (rem > 0) {
            int sv = svn;
            if constexpr (NG == 4) {
                if (grp < rem) ROW_ADD(__shfl(sv, grp));
                if (grp + 4 < rem) ROW_ADD(__shfl(sv, grp + 4));
            } else {
                if (grp < rem) ROW_ADD(__shfl(sv, grp));
            }
        }
    }
#undef ROW_ADD

#define RED(a)                                                  \
    do {                                                        \
        if constexpr (NG == 8) a += __shfl_xor(a, 8);           \
        a += __shfl_xor(a, 16);                                 \
        a += __shfl_xor(a, 32);                                 \
    } while (0)
    RED(a0); RED(a1); RED(a2); RED(a3);
    RED(a4); RED(a5); RED(a6); RED(a7);
#undef RED

    if (grp == 0) {
        const float di = dis[node];
        uint4 sv4 = *(const uint4*)(hW + (size_t)node * F + gl * 8);
        float v0 = (a0 + bf16lo(sv4.x)) * di;
        float v1 = (a1 + bf16hi(sv4.x)) * di;
        float v2 = (a2 + bf16lo(sv4.y)) * di;
        float v3 = (a3 + bf16hi(sv4.y)) * di;
        float v4 = (a4 + bf16lo(sv4.z)) * di;
        float v5 = (a5 + bf16hi(sv4.z)) * di;
        float v6 = (a6 + bf16lo(sv4.w)) * di;
        float v7 = (a7 + bf16hi(sv4.w)) * di;
        if constexpr (BIAS) {
            float4 b0 = *(const float4*)(bias + gl * 8);
            float4 b1 = *(const float4*)(bias + gl * 8 + 4);
            v0 += b0.x; v1 += b0.y; v2 += b0.z; v3 += b0.w;
            v4 += b1.x; v5 += b1.y; v6 += b1.z; v7 += b1.w;
        }
        if constexpr (RELU) {
            v0 = fmaxf(v0, 0.f); v1 = fmaxf(v1, 0.f);
            v2 = fmaxf(v2, 0.f); v3 = fmaxf(v3, 0.f);
            v4 = fmaxf(v4, 0.f); v5 = fmaxf(v5, 0.f);
            v6 = fmaxf(v6, 0.f); v7 = fmaxf(v7, 0.f);
        }
        if constexpr (OB) {
            uint4 o;
            o.x = (unsigned)bf16rne(v0) | ((unsigned)bf16rne(v1) << 16);
            o.y = (unsigned)bf16rne(v2) | ((unsigned)bf16rne(v3) << 16);
            o.z = (unsigned)bf16rne(v4) | ((unsigned)bf16rne(v5) << 16);
            o.w = (unsigned)bf16rne(v6) | ((unsigned)bf16rne(v7) << 16);
            *(uint4*)((unsigned short*)outv + (size_t)node * F + gl * 8) = o;
        } else {
            float* orow = (float*)outv + (size_t)node * F + gl * 8;
            *(float4*)orow = make_float4(v0, v1, v2, v3);
            *(float4*)(orow + 4) = make_float4(v4, v5, v6, v7);
        }
    }
}

// ---------------- launch -----------------------------------------------------

extern "C" void kernel_launch(void* const* d_in, const int* in_sizes, int n_in,
                              void* d_out, int out_size, void* d_ws, size_t ws_size,
                              hipStream_t stream) {
    const float* x   = (const float*)d_in[0];
    const float* st  = (const float*)d_in[1];
    const int*   src = (const int*)d_in[2];
    const int*   dst = (const int*)d_in[3];
    const float* W1  = (const float*)d_in[4];
    const float* b1  = (const float*)d_in[5];
    const float* W2  = (const float*)d_in[6];
    const float* b2  = (const float*)d_in[7];
    const float* Wg0 = (const float*)d_in[8];
    const float* bg0 = (const float*)d_in[9];
    const float* Wg1 = (const float*)d_in[10];
    const float* bg1 = (const float*)d_in[11];
    const float* Wg2 = (const float*)d_in[12];
    const float* bg2 = (const float*)d_in[13];

    const int n = in_sizes[0] / 64;  // IN_DIM = 64
    const int e = in_sizes[2];
    const int nb = (n + 255) >> 8;

    char* wp = (char*)d_ws;
    auto carve = [&](size_t bytes) {
        void* p = (void*)wp;
        wp += (bytes + 255) & ~(size_t)255;
        return p;
    };
    int*   ghist = (int*)carve(512 * 4);
    int*   gcur  = (int*)carve(512 * 4);
    int*   bbase = (int*)carve(513 * 4);
    int*   offs  = (int*)carve((size_t)(n + 1) * 4);
    float* dis   = (float*)carve((size_t)n * 4);
    int*   ssrc  = (int*)carve((size_t)e * 4);
    char*  R3    = (char*)carve((size_t)n * 128 * 4);  // ep -> A -> h1|h2
    char*  R2    = (char*)carve((size_t)n * 64 * 2);   // h0 -> Q
    unsigned short* Waf = (unsigned short*)carve((size_t)96 * 128 * 2);
    unsigned short* Wbf = (unsigned short*)carve((size_t)128 * 64 * 2);
    unsigned short* W0f = (unsigned short*)carve((size_t)64 * 128 * 2);
    unsigned short* W1f = (unsigned short*)carve((size_t)128 * 128 * 2);
    unsigned short* W2f = (unsigned short*)carve((size_t)128 * 64 * 2);

    // aliases (stream-ordered lifetimes):
    int2* ep = (int2*)R3;                                 // dead after k_build
    unsigned short* A  = (unsigned short*)R3;             // mmx1 out (n*128 bf16)
    unsigned short* h1 = (unsigned short*)R3;             // mmx3 out (A dead by then)
    unsigned short* h2 = (unsigned short*)(R3 + (size_t)n * 128 * 2);  // agg1 out
    unsigned short* h0 = (unsigned short*)R2;             // mmx2 out (dis-scaled)
    unsigned short* Q  = (unsigned short*)R2;             // mmx5 out (dis-scaled)
    unsigned short* a0 = (unsigned short*)d_out;          // agg0 out (n*64 bf16)
    unsigned short* P  = (unsigned short*)d_out;          // mmx4 out (n*128 bf16)

    hipMemsetAsync(ghist, 0, 512 * 4, stream);

    const int gN64 = (n + 63) / 64;
    const int gAgg = (n + 3) / 4;
    const int gE4k = (e + 4095) / 4096;

    // graph prep
    k_hist<<<gE4k, 256, 0, stream>>>(dst, e, nb, ghist);
    k_scan<<<1, 512, 0, stream>>>(ghist, nb, e, n, bbase, gcur, offs);
    k_scatter1<<<gE4k, 256, 0, stream>>>(src, dst, e, nb, gcur, ep);
    k_build<<<nb, 256, 0, stream>>>(ep, bbase, n, offs, ssrc, dis);
    k_sort<<<gAgg, 256, 0, stream>>>(offs, ssrc, n);

    // W fragment prep (fused x5): 53248 elements = 208 blocks
    k_wprep5<<<208, 256, 0, stream>>>(W1, W2, Wg0, Wg1, Wg2, Waf, Wbf, W0f, W1f, W2f);

    // MLP on MFMA: A = relu([x|st]@W1+b1); h0 = dis*relu(A@W2+b2)
    k_mmx1<<<gN64, 256, 0, stream>>>(x, st, Waf, b1, A, n);
    k_mmx<128, 64, true, true, true><<<gN64, 256, 0, stream>>>(A, Wbf, b2, dis, h0, n);

    // conv0: agg FIRST at F=64 (agg(h)@W == agg(h@W)), then MFMA w/ bias+relu
    k_agg<64, false, true, false><<<gAgg, 256, 0, stream>>>(h0, nullptr, dis, offs, ssrc, a0, n);
    k_mmx<64, 128, true, true, false><<<gN64, 256, 0, stream>>>(a0, W0f, bg0, nullptr, h1, n);

    // conv1: MFMA mm (dis-prescaled) -> agg@128 (dis+bias+relu, bf16 out)
    k_mmx<128, 128, false, false, true><<<gN64, 256, 0, stream>>>(h1, W1f, nullptr, dis, P, n);
    k_agg<128, true, true, true><<<gAgg, 256, 0, stream>>>(P, bg1, dis, offs, ssrc, h2, n);

    // conv2: MFMA mm (dis-prescaled) -> agg@64 (dis+bias, fp32 out) -> d_out
    k_mmx<128, 64, false, false, true><<<gN64, 256, 0, stream>>>(h2, W2f, nullptr, dis, Q, n);
    k_agg<64, false, false, true><<<gAgg, 256, 0, stream>>>(Q, bg2, dis, offs, ssrc,
                                                            (float*)d_out, n);
}